// Round 1
// baseline (342.978 us; speedup 1.0000x reference)
//
#include <hip/hip_runtime.h>

// Upsample 2x via depthwise transposed conv, FIR k1=[1,3,3,1], factor=2.
// Separable: out[2i]   = (x[i-1] + 3*x[i]) / 4
//            out[2i+1] = (3*x[i] + x[i+1]) / 4   (zero padding at edges)
// Input  (B=8, C=128, H=128, W=128) fp32
// Output (B=8, C=128, 256, 256) fp32

#define IN_H 128
#define IN_W 128

__global__ __launch_bounds__(256) void upsample_fir_kernel(
    const float* __restrict__ x, float* __restrict__ out, int total) {
    int t = blockIdx.x * blockDim.x + threadIdx.x;
    if (t >= total) return;

    int ix = t & (IN_W - 1);
    int iy = (t >> 7) & (IN_H - 1);
    int bc = t >> 14;  // fused batch*channel index

    const float* xp = x + (size_t)bc * IN_H * IN_W;

    // 3x3 neighborhood with zero boundary
    float v[3][3];
#pragma unroll
    for (int dy = -1; dy <= 1; ++dy) {
        int yy = iy + dy;
        bool yok = (unsigned)yy < IN_H;
#pragma unroll
        for (int dx = -1; dx <= 1; ++dx) {
            int xx = ix + dx;
            bool ok = yok && ((unsigned)xx < IN_W);
            v[dy + 1][dx + 1] = ok ? xp[yy * IN_W + xx] : 0.0f;
        }
    }

    // horizontal pass per row
    float he[3], ho[3];
#pragma unroll
    for (int r = 0; r < 3; ++r) {
        he[r] = (v[r][0] + 3.0f * v[r][1]) * 0.25f;
        ho[r] = (3.0f * v[r][1] + v[r][2]) * 0.25f;
    }

    // vertical pass -> 2x2 output block
    float2 top, bot;
    top.x = (he[0] + 3.0f * he[1]) * 0.25f;
    top.y = (ho[0] + 3.0f * ho[1]) * 0.25f;
    bot.x = (3.0f * he[1] + he[2]) * 0.25f;
    bot.y = (3.0f * ho[1] + ho[2]) * 0.25f;

    const int OW = 2 * IN_W;
    size_t ob = (size_t)bc * (2 * IN_H) * OW + (size_t)(2 * iy) * OW + 2 * ix;
    *(float2*)(out + ob) = top;
    *(float2*)(out + ob + OW) = bot;
}

extern "C" void kernel_launch(void* const* d_in, const int* in_sizes, int n_in,
                              void* d_out, int out_size, void* d_ws, size_t ws_size,
                              hipStream_t stream) {
    const float* x = (const float*)d_in[0];
    float* out = (float*)d_out;
    int total = in_sizes[0];  // 8*128*128*128 = 16777216
    int threads = 256;
    int blocks = (total + threads - 1) / threads;
    upsample_fir_kernel<<<blocks, threads, 0, stream>>>(x, out, total);
}

// Round 2
// 334.389 us; speedup vs baseline: 1.0257x; 1.0257x over previous
//
#include <hip/hip_runtime.h>

// Upsample 2x depthwise transposed conv, FIR k1=[1,3,3,1], factor=2 (separable).
// out[2i]   = (x[i-1] + 3*x[i]) / 4
// out[2i+1] = (3*x[i] + x[i+1]) / 4   (zero padding at edges)
// Input (8,128,128,128) fp32 -> Output (8,128,256,256) fp32
//
// Layout: 32 lanes cover one 128-px input row (4 px/lane, float4 loads).
// A 64-lane wave covers 2 rows; block of 256 covers 8 rows.
// Vertical pass in registers, horizontal neighbors via __shfl (the 32-lane
// group boundary coincides with the image x-boundary, so cross-row shuffle
// pollution is masked to zero).

#define IN_H 128
#define IN_W 128

__global__ __launch_bounds__(256) void upsample_fir_kernel(
    const float* __restrict__ x, float* __restrict__ out) {
    const int tid = threadIdx.x;
    const int lane32 = tid & 31;
    const int r = blockIdx.x * 8 + (tid >> 5);   // global input row index
    const int bc = r >> 7;                        // batch*channel
    const int iy = r & (IN_H - 1);

    const float* xp = x + (size_t)bc * (IN_H * IN_W);
    const float4 z4 = make_float4(0.f, 0.f, 0.f, 0.f);

    const float4* rowm = (const float4*)(xp + (iy - 1) * IN_W);
    const float4* row0 = (const float4*)(xp + iy * IN_W);
    const float4* rowp = (const float4*)(xp + (iy + 1) * IN_W);

    float4 a = (iy > 0) ? rowm[lane32] : z4;
    float4 b = row0[lane32];
    float4 c = (iy < IN_H - 1) ? rowp[lane32] : z4;

    // vertical pass: t = row 2*iy contribution, u = row 2*iy+1
    float4 t, u;
    t.x = (a.x + 3.f * b.x) * 0.25f;  u.x = (3.f * b.x + c.x) * 0.25f;
    t.y = (a.y + 3.f * b.y) * 0.25f;  u.y = (3.f * b.y + c.y) * 0.25f;
    t.z = (a.z + 3.f * b.z) * 0.25f;  u.z = (3.f * b.z + c.z) * 0.25f;
    t.w = (a.w + 3.f * b.w) * 0.25f;  u.w = (3.f * b.w + c.w) * 0.25f;

    // horizontal neighbors via wave shuffle (width 64; 32-boundary == image edge)
    float t_l = __shfl_up(t.w, 1);   if (lane32 == 0)  t_l = 0.f;
    float t_r = __shfl_down(t.x, 1); if (lane32 == 31) t_r = 0.f;
    float u_l = __shfl_up(u.w, 1);   if (lane32 == 0)  u_l = 0.f;
    float u_r = __shfl_down(u.x, 1); if (lane32 == 31) u_r = 0.f;

    // horizontal pass -> 8 outputs per row
    float4 o0, o1, p0, p1;
    o0.x = (t_l + 3.f * t.x) * 0.25f;
    o0.y = (3.f * t.x + t.y) * 0.25f;
    o0.z = (t.x + 3.f * t.y) * 0.25f;
    o0.w = (3.f * t.y + t.z) * 0.25f;
    o1.x = (t.y + 3.f * t.z) * 0.25f;
    o1.y = (3.f * t.z + t.w) * 0.25f;
    o1.z = (t.z + 3.f * t.w) * 0.25f;
    o1.w = (3.f * t.w + t_r) * 0.25f;

    p0.x = (u_l + 3.f * u.x) * 0.25f;
    p0.y = (3.f * u.x + u.y) * 0.25f;
    p0.z = (u.x + 3.f * u.y) * 0.25f;
    p0.w = (3.f * u.y + u.z) * 0.25f;
    p1.x = (u.y + 3.f * u.z) * 0.25f;
    p1.y = (3.f * u.z + u.w) * 0.25f;
    p1.z = (u.z + 3.f * u.w) * 0.25f;
    p1.w = (3.f * u.w + u_r) * 0.25f;

    const int OW = 2 * IN_W;
    float* ob = out + (size_t)bc * (2 * IN_H) * OW + (size_t)(2 * iy) * OW + 8 * lane32;
    *(float4*)(ob) = o0;
    *(float4*)(ob + 4) = o1;
    *(float4*)(ob + OW) = p0;
    *(float4*)(ob + OW + 4) = p1;
}

extern "C" void kernel_launch(void* const* d_in, const int* in_sizes, int n_in,
                              void* d_out, int out_size, void* d_ws, size_t ws_size,
                              hipStream_t stream) {
    const float* x = (const float*)d_in[0];
    float* out = (float*)d_out;
    // total input rows = B*C*H = 8*128*128 = 131072; 8 rows per block
    int blocks = (8 * 128 * 128) / 8;  // 16384
    upsample_fir_kernel<<<blocks, 256, 0, stream>>>(x, out);
}